// Round 1
// baseline (60.066 us; speedup 1.0000x reference)
//
#include <hip/hip_runtime.h>

// LIF scan: B=65536 rows, L=400 timesteps, sequential over t per row.
//   v = v + (-v/20 + I_t)        (IEEE divide kept: must match numpy fp32 bit-exactly,
//                                 else borderline threshold crossings flip spikes and
//                                 argmax-based hard_latency blows the 7.2 threshold)
//   spike = (v >= 1.0), then hard reset v=0 on spike.
// Outputs concatenated in d_out (float32):
//   [0, B*L)          spikes, row-major
//   [B*L, B*L+B)      hard_latency (first spike index, 0 if none) as float
//   [B*L+B, B*L+2B)   soft_latency = (sum t*s) / (sum s + 1e-6)

#define LIF_L 400
#define LIF_NT4 (LIF_L / 4)

__global__ __launch_bounds__(256) void lif_kernel(const float* __restrict__ I,
                                                  float* __restrict__ spikes,
                                                  float* __restrict__ hard_lat,
                                                  float* __restrict__ soft_lat,
                                                  int B) {
    int row = blockIdx.x * blockDim.x + threadIdx.x;
    if (row >= B) return;

    const float4* Irow = reinterpret_cast<const float4*>(I + (size_t)row * LIF_L);
    float4* Srow = reinterpret_cast<float4*>(spikes + (size_t)row * LIF_L);

    float v = 0.0f;
    float num = 0.0f;   // sum t * spike_t  (exact: integer-valued, < 79800)
    int cnt = 0;        // sum spike_t
    int first = 0x7fffffff;

#pragma unroll 5
    for (int t4 = 0; t4 < LIF_NT4; ++t4) {
        float4 c = Irow[t4];
        float in[4] = {c.x, c.y, c.z, c.w};
        float sp[4];
#pragma unroll
        for (int j = 0; j < 4; ++j) {
            int t = t4 * 4 + j;
            // replicate reference association: v = v + ((-v/TAU) + It)
            float d = (-(v / 20.0f)) + in[j];
            v = v + d;
            bool fire = (v >= 1.0f);
            float spv = fire ? 1.0f : 0.0f;
            num += spv * (float)t;
            cnt += fire ? 1 : 0;
            first = (fire && first == 0x7fffffff) ? t : first;
            v = fire ? 0.0f : v;
            sp[j] = spv;
        }
        float4 s;
        s.x = sp[0]; s.y = sp[1]; s.z = sp[2]; s.w = sp[3];
        Srow[t4] = s;
    }

    int hard = (first == 0x7fffffff) ? 0 : first;
    hard_lat[row] = (float)hard;
    soft_lat[row] = num / ((float)cnt + 1e-6f);
}

extern "C" void kernel_launch(void* const* d_in, const int* in_sizes, int n_in,
                              void* d_out, int out_size, void* d_ws, size_t ws_size,
                              hipStream_t stream) {
    const float* I = (const float*)d_in[0];
    int B = in_sizes[0] / LIF_L;  // 65536

    float* spikes = (float*)d_out;
    float* hard = spikes + (size_t)B * LIF_L;
    float* soft = hard + B;

    dim3 block(256);
    dim3 grid((B + 255) / 256);
    hipLaunchKernelGGL(lif_kernel, grid, block, 0, stream, I, spikes, hard, soft, B);
}

// Round 2
// 55.201 us; speedup vs baseline: 1.0881x; 1.0881x over previous
//
#include <hip/hip_runtime.h>

// LIF scan, B=65536 rows x L=400 steps, sequential per row.
// Round 2: block = 256 threads = 256 rows. Chunked LDS pipeline, TC=80 steps:
//   1) coop coalesced global->reg load of chunk (320B/row segments, 64B-line aligned)
//   2) reg->LDS (padded row = 81 floats -> bank pattern (r*17+t)%32, 2-way = free)
//   3) per-thread scan of own row from LDS, spikes written back in-place
//   4) coop coalesced LDS->global store (full-line 320B segments -> no partial-line
//      write amplification; round-1 counters showed 172MB written vs 105MB ideal)
// Next chunk's global loads are issued before the compute phase so ~900cy HBM
// latency hides under ~3800cy of scan compute (1 wave/SIMD, ILP-only hiding).
//
// IEEE divide v/20 kept: must match numpy fp32 bit-exactly or borderline
// threshold crossings flip spikes and argmax hard_latency blows the threshold.

#define L_LEN 400
#define TC 80                 // timesteps per chunk (320B per row: 64B-line aligned)
#define NC (L_LEN / TC)       // 5 chunks
#define ROWS 256              // rows per block
#define PADL 81               // padded LDS row length (conflict-free)
#define F4T 20                // float4 loads per thread per chunk (256*80/4/256)

__device__ __forceinline__ void load_regs(const float* __restrict__ I,
                                          int R0, int c, int j, float4* regs) {
#pragma unroll
    for (int i = 0; i < F4T; ++i) {
        int flat = i * 256 + j;          // 0..5119
        int r = flat / F4T;              // row within block (magic-mul)
        int k = flat % F4T;              // float4 index within row chunk
        regs[i] = *reinterpret_cast<const float4*>(
            I + (size_t)(R0 + r) * L_LEN + c * TC + k * 4);
    }
}

__global__ __launch_bounds__(256, 1) void lif_kernel(const float* __restrict__ I,
                                                     float* __restrict__ spikes,
                                                     float* __restrict__ hard_lat,
                                                     float* __restrict__ soft_lat) {
    __shared__ float lds[ROWS * PADL];   // 82944 B
    const int j = threadIdx.x;
    const int R0 = blockIdx.x * ROWS;

    float4 regs[F4T];

    float v = 0.0f;
    float num = 0.0f;       // sum t*spike (integer-valued, exact in fp32)
    int cnt = 0;            // sum spike
    int first = 0x7fffffff; // first spike index

    load_regs(I, R0, 0, j, regs);

    for (int c = 0; c < NC; ++c) {
        // regs -> LDS (compiler inserts vmcnt waits on reg use)
#pragma unroll
        for (int i = 0; i < F4T; ++i) {
            int flat = i * 256 + j;
            int r = flat / F4T;
            int k = flat % F4T;
            float* p = &lds[r * PADL + k * 4];
            p[0] = regs[i].x; p[1] = regs[i].y; p[2] = regs[i].z; p[3] = regs[i].w;
        }
        __syncthreads();

        if (c + 1 < NC) load_regs(I, R0, c + 1, j, regs);  // hide under compute

        // scan own row for this chunk; overwrite input with spike in-place
        float* myrow = &lds[j * PADL];
#pragma unroll 8
        for (int t = 0; t < TC; ++t) {
            int t_abs = c * TC + t;
            float x = myrow[t];
            // reference association: v = v + ((-v/TAU) + It), IEEE divide
            float d = (-(v / 20.0f)) + x;
            v = v + d;
            bool fire = (v >= 1.0f);
            float spv = fire ? 1.0f : 0.0f;
            num += spv * (float)t_abs;
            cnt += fire ? 1 : 0;
            first = (fire && first == 0x7fffffff) ? t_abs : first;
            v = fire ? 0.0f : v;
            myrow[t] = spv;
        }
        __syncthreads();

        // coop store: full-line 320B contiguous segments per row
#pragma unroll
        for (int i = 0; i < F4T; ++i) {
            int flat = i * 256 + j;
            int r = flat / F4T;
            int k = flat % F4T;
            const float* p = &lds[r * PADL + k * 4];
            float4 s;
            s.x = p[0]; s.y = p[1]; s.z = p[2]; s.w = p[3];
            *reinterpret_cast<float4*>(
                spikes + (size_t)(R0 + r) * L_LEN + c * TC + k * 4) = s;
        }
        __syncthreads();  // store-phase ds_reads must finish before next ds_write
    }

    int hard = (first == 0x7fffffff) ? 0 : first;
    hard_lat[R0 + j] = (float)hard;
    soft_lat[R0 + j] = num / ((float)cnt + 1e-6f);
}

extern "C" void kernel_launch(void* const* d_in, const int* in_sizes, int n_in,
                              void* d_out, int out_size, void* d_ws, size_t ws_size,
                              hipStream_t stream) {
    const float* I = (const float*)d_in[0];
    int B = in_sizes[0] / L_LEN;  // 65536

    float* spk = (float*)d_out;
    float* hard = spk + (size_t)B * L_LEN;
    float* soft = hard + B;

    dim3 block(256);
    dim3 grid(B / ROWS);  // 256 blocks -> 1 per CU
    hipLaunchKernelGGL(lif_kernel, grid, block, 0, stream, I, spk, hard, soft);
}

// Round 3
// 42.240 us; speedup vs baseline: 1.4220x; 1.3068x over previous
//
#include <hip/hip_runtime.h>

// LIF scan, B=65536 rows x L=400, sequential per row.
// Round 3: block = 64 threads = 1 wave = 64 rows; grid = 1024 (4 blocks/CU).
// Parallelism is hard-capped at 1 wave/SIMD (65536 threads total), so the design
// removes every stall source instead of adding waves:
//   - input read DIRECTLY to registers (20 float4/chunk, 2-chunk double buffer);
//     scan phase is pure VALU, no ds_read, no barriers (single-wave lockstep).
//   - spikes bit-packed (80 bits -> 3 u32) -> 768B LDS exchange -> coalesced
//     full-line float4 stores (keeps round-2's WRITE_SIZE=105MB ideal).
//   - division by 20 via Markstein 2-fma refinement (q=v*c; r=fma(-20,q,v);
//     q'=fma(r,c,q)): correctly-rounded quotient, chain ~28cy/step vs ~48 with
//     the IEEE div expansion. If absmax regresses, revert to v/20.0f.
//   - cnt/first derived from the bit words (popcount/ctz) per chunk, off-chain.

#define L_LEN 400
#define TC 80                 // timesteps per chunk (320B/row = 5 full lines)
#define NC 5
#define F4C 20                // float4 per chunk per row
#define BIG 0x7fffffff

__device__ __forceinline__ float div20(float v) {
    const float c = 0.05f;           // RN(1/20)
    float q = v * c;
    float r = fmaf(-20.0f, q, v);    // exact residual via fma
    return fmaf(r, c, q);            // correctly-rounded v/20
}

__device__ __forceinline__ void load_chunk(const float* __restrict__ I, int row,
                                           int c, float4* regs) {
#pragma unroll
    for (int k = 0; k < F4C; ++k)
        regs[k] = *reinterpret_cast<const float4*>(
            I + (size_t)row * L_LEN + c * TC + k * 4);
}

struct ScanState {
    float v;
    int num;    // sum t*spike (absolute t), exact in int
    int cnt;
    int first;  // BIG if none
};

__device__ __forceinline__ void scan_chunk(const float4* in, int cbase,
                                           ScanState& st, unsigned* bw) {
    unsigned b0 = 0, b1 = 0, b2 = 0;
    int numL = 0;  // sum of LOCAL t (0..79) over fires this chunk
#pragma unroll
    for (int k = 0; k < F4C; ++k) {
        float x[4] = {in[k].x, in[k].y, in[k].z, in[k].w};
#pragma unroll
        for (int m = 0; m < 4; ++m) {
            const int tl = k * 4 + m;               // compile-time 0..79
            // reference: t1 = (-v)/20; t2 = t1 + x; v = v + t2
            float d  = x[m] - div20(st.v);
            float vn = st.v + d;
            bool fire = vn >= 1.0f;
            numL = fire ? numL + tl : numL;
            if (tl < 32)      b0 |= fire ? (1u << tl) : 0u;
            else if (tl < 64) b1 |= fire ? (1u << (tl - 32)) : 0u;
            else              b2 |= fire ? (1u << (tl - 64)) : 0u;
            st.v = fire ? 0.0f : vn;
        }
    }
    int cntC = __builtin_popcount(b0) + __builtin_popcount(b1) +
               __builtin_popcount(b2);
    int fl = b0 ? __builtin_ctz(b0)
           : (b1 ? 32 + __builtin_ctz(b1)
           : (b2 ? 64 + __builtin_ctz(b2) : -1));
    st.num += numL + cbase * cntC;
    st.cnt += cntC;
    st.first = min(st.first, fl >= 0 ? cbase + fl : BIG);
    bw[0] = b0; bw[1] = b1; bw[2] = b2;
}

__global__ __launch_bounds__(64, 1) void lif_kernel(const float* __restrict__ I,
                                                    float* __restrict__ spikes,
                                                    float* __restrict__ hard_lat,
                                                    float* __restrict__ soft_lat) {
    __shared__ unsigned bits[64][3];   // 768B; single wave -> no barriers needed
    const int j = threadIdx.x;
    const int R0 = blockIdx.x * 64;
    const int row = R0 + j;

    float4 A[F4C], B[F4C];
    load_chunk(I, row, 0, A);
    load_chunk(I, row, 1, B);

    ScanState st;
    st.v = 0.0f; st.num = 0; st.cnt = 0; st.first = BIG;

    for (int c = 0; c < NC; ++c) {
        unsigned bw[3];
        if ((c & 1) == 0) {
            scan_chunk(A, c * TC, st, bw);
            if (c + 2 < NC) load_chunk(I, row, c + 2, A);
        } else {
            scan_chunk(B, c * TC, st, bw);
            if (c + 2 < NC) load_chunk(I, row, c + 2, B);
        }
        bits[j][0] = bw[0]; bits[j][1] = bw[1]; bits[j][2] = bw[2];
        // wave-lockstep: compiler orders ds_write->ds_read via lgkmcnt; no barrier.
#pragma unroll
        for (int i = 0; i < F4C; ++i) {
            int flat = i * 64 + j;          // 0..1279
            int rl = flat / F4C;            // row within block's 64
            int k  = flat % F4C;            // float4 index 0..19
            unsigned w = bits[rl][k >> 3];
            int sh = (4 * k) & 31;          // nibble position (never straddles)
            float4 s;
            s.x = (float)((w >> (sh + 0)) & 1u);
            s.y = (float)((w >> (sh + 1)) & 1u);
            s.z = (float)((w >> (sh + 2)) & 1u);
            s.w = (float)((w >> (sh + 3)) & 1u);
            *reinterpret_cast<float4*>(
                spikes + (size_t)(R0 + rl) * L_LEN + c * TC + k * 4) = s;
        }
    }

    hard_lat[row] = (float)(st.first == BIG ? 0 : st.first);
    soft_lat[row] = (float)st.num / ((float)st.cnt + 1e-6f);
}

extern "C" void kernel_launch(void* const* d_in, const int* in_sizes, int n_in,
                              void* d_out, int out_size, void* d_ws, size_t ws_size,
                              hipStream_t stream) {
    const float* I = (const float*)d_in[0];
    int B = in_sizes[0] / L_LEN;  // 65536

    float* spk = (float*)d_out;
    float* hard = spk + (size_t)B * L_LEN;
    float* soft = hard + B;

    dim3 block(64);
    dim3 grid(B / 64);  // 1024 blocks
    hipLaunchKernelGGL(lif_kernel, grid, block, 0, stream, I, spk, hard, soft);
}